// Round 1
// baseline (498.177 us; speedup 1.0000x reference)
//
#include <hip/hip_runtime.h>
#include <hip/hip_bf16.h>

// NestedFeedForward: x[16384,1024] fp32, w1[4096,1024], b1[4096], w2[1024,4096],
// b2[1024], token_mask[16384] in [0,4).
//   d(t) = 1024 >> (3 - mask[t])
//   h = gelu_erf( mask_in(x) @ w1^T + b1 )        (hidden always full 4096)
//   y = mask_out( h @ w2^T + b2 )
// Round 0: bf16 MFMA baseline, full GEMMs with zero-masking (no token grouping yet).

typedef __bf16 bf16x8 __attribute__((ext_vector_type(8)));
typedef float f32x4 __attribute__((ext_vector_type(4)));

#define M_TOK   16384
#define DIM     1024
#define HID     4096

__device__ inline unsigned short f2bf(float f) {
  unsigned int u = __float_as_uint(f);
  u += 0x7fffu + ((u >> 16) & 1u);      // RNE; inputs are finite, no NaN path needed
  return (unsigned short)(u >> 16);
}

__device__ inline void async_copy16(const void* g, void* s) {
  __builtin_amdgcn_global_load_lds(
      (const __attribute__((address_space(1))) unsigned int*)g,
      (__attribute__((address_space(3))) unsigned int*)s,
      16, 0, 0);
}

// Stage a 128-row x 64-col bf16 tile (row-major global, leading dim LDK elems)
// into 16 KB of LDS. XOR-swizzle the eight 16B chunks of each 128B row by
// (row&7) so the MFMA-fragment ds_read_b128s are 2-way (free) instead of 8-way.
template<int LDK>
__device__ inline void stage_tile(const unsigned short* __restrict__ g,
                                  int row0, int k0, char* lds) {
  const char* gbase = (const char*)g;
  int tid = threadIdx.x;
#pragma unroll
  for (int i = 0; i < 4; ++i) {
    int q = i * 256 + tid;          // 1024 chunks of 16B
    int r = q >> 3;                 // tile row 0..127
    int c = q & 7;                  // LDS chunk within row
    int gc = c ^ (r & 7);           // swizzled source chunk
    const void* gp = gbase + ((size_t)(row0 + r) * LDK + (size_t)k0 + gc * 8) * 2;
    async_copy16(gp, lds + (size_t)q * 16);
  }
}

// ---- GEMM1: h[t,f] = gelu( sum_d xb[t,d]*w1b[f,d] + b1[f] ), store bf16 ----
__global__ __launch_bounds__(256) void gemm1_kernel(
    const unsigned short* __restrict__ A,   // xb [16384,1024] bf16
    const unsigned short* __restrict__ B,   // w1b [4096,1024] bf16
    const float* __restrict__ bias,         // b1 [4096]
    unsigned short* __restrict__ H)         // hb [16384,4096] bf16
{
  constexpr int K = DIM, N = HID;
  __shared__ char smem[32768];
  char* As = smem;
  char* Bs = smem + 16384;
  int tid = threadIdx.x;
  int lane = tid & 63, quad = lane >> 4, l15 = lane & 15;
  int wave = tid >> 6, wm = wave & 1, wn = wave >> 1;
  int row0 = blockIdx.x * 128, col0 = blockIdx.y * 128;

  f32x4 acc[4][4] = {};

  for (int k0 = 0; k0 < K; k0 += 64) {
    __syncthreads();
    stage_tile<K>(A, row0, k0, As);
    stage_tile<K>(B, col0, k0, Bs);
    __syncthreads();
#pragma unroll
    for (int kk = 0; kk < 2; ++kk) {
      bf16x8 af[4], bg[4];
#pragma unroll
      for (int mt = 0; mt < 4; ++mt) {
        int m = wm * 64 + mt * 16 + l15;
        int ch = (kk * 4 + quad) ^ (m & 7);
        af[mt] = *(const bf16x8*)(As + m * 128 + ch * 16);
      }
#pragma unroll
      for (int nt = 0; nt < 4; ++nt) {
        int n = wn * 64 + nt * 16 + l15;
        int ch = (kk * 4 + quad) ^ (n & 7);
        bg[nt] = *(const bf16x8*)(Bs + n * 128 + ch * 16);
      }
#pragma unroll
      for (int mt = 0; mt < 4; ++mt)
#pragma unroll
        for (int nt = 0; nt < 4; ++nt)
          acc[mt][nt] = __builtin_amdgcn_mfma_f32_16x16x32_bf16(
              af[mt], bg[nt], acc[mt][nt], 0, 0, 0);
    }
  }

  // Epilogue: C/D layout col=lane&15 (N), row=quad*4+reg (M)  [m89/m91-verified]
  int t_base = row0 + wm * 64;
  int f_base = col0 + wn * 64;
#pragma unroll
  for (int nt = 0; nt < 4; ++nt) {
    int f = f_base + nt * 16 + l15;
    float bv = bias[f];
#pragma unroll
    for (int mt = 0; mt < 4; ++mt) {
#pragma unroll
      for (int r = 0; r < 4; ++r) {
        int t = t_base + mt * 16 + quad * 4 + r;
        float v = acc[mt][nt][r] + bv;
        v = 0.5f * v * (1.0f + erff(v * 0.7071067811865475f));  // exact-erf GELU
        H[(size_t)t * N + f] = f2bf(v);
      }
    }
  }
}

// ---- GEMM2: y[t,d] = (d < dout(t)) ? sum_f hb[t,f]*w2b[d,f] + b2[d] : 0 ----
__global__ __launch_bounds__(256) void gemm2_kernel(
    const unsigned short* __restrict__ A,   // hb [16384,4096] bf16
    const unsigned short* __restrict__ B,   // w2b [1024,4096] bf16
    const float* __restrict__ bias,         // b2 [1024]
    const int* __restrict__ tmask,          // [16384]
    float* __restrict__ out)                // [16384,1024] fp32
{
  constexpr int K = HID, N = DIM;
  __shared__ char smem[32768];
  char* As = smem;
  char* Bs = smem + 16384;
  int tid = threadIdx.x;
  int lane = tid & 63, quad = lane >> 4, l15 = lane & 15;
  int wave = tid >> 6, wm = wave & 1, wn = wave >> 1;
  int row0 = blockIdx.x * 128, col0 = blockIdx.y * 128;

  f32x4 acc[4][4] = {};

  for (int k0 = 0; k0 < K; k0 += 64) {
    __syncthreads();
    stage_tile<K>(A, row0, k0, As);
    stage_tile<K>(B, col0, k0, Bs);
    __syncthreads();
#pragma unroll
    for (int kk = 0; kk < 2; ++kk) {
      bf16x8 af[4], bg[4];
#pragma unroll
      for (int mt = 0; mt < 4; ++mt) {
        int m = wm * 64 + mt * 16 + l15;
        int ch = (kk * 4 + quad) ^ (m & 7);
        af[mt] = *(const bf16x8*)(As + m * 128 + ch * 16);
      }
#pragma unroll
      for (int nt = 0; nt < 4; ++nt) {
        int n = wn * 64 + nt * 16 + l15;
        int ch = (kk * 4 + quad) ^ (n & 7);
        bg[nt] = *(const bf16x8*)(Bs + n * 128 + ch * 16);
      }
#pragma unroll
      for (int mt = 0; mt < 4; ++mt)
#pragma unroll
        for (int nt = 0; nt < 4; ++nt)
          acc[mt][nt] = __builtin_amdgcn_mfma_f32_16x16x32_bf16(
              af[mt], bg[nt], acc[mt][nt], 0, 0, 0);
    }
  }

  int t_base = row0 + wm * 64;
  int d_base = col0 + wn * 64;
#pragma unroll
  for (int nt = 0; nt < 4; ++nt) {
    int d = d_base + nt * 16 + l15;
    float bv = bias[d];
#pragma unroll
    for (int mt = 0; mt < 4; ++mt) {
#pragma unroll
      for (int r = 0; r < 4; ++r) {
        int t = t_base + mt * 16 + quad * 4 + r;
        int dout = DIM >> (3 - tmask[t]);
        float v = acc[mt][nt][r] + bv;
        out[(size_t)t * N + d] = (d < dout) ? v : 0.0f;  // poisoned out needs explicit zeros
      }
    }
  }
}

// ---- conversions ----
// x fp32 -> bf16, zeroing features >= d_in(t) (exactly equivalent to truncation)
__global__ void cvt_x_kernel(const float* __restrict__ x, const int* __restrict__ tm,
                             unsigned short* __restrict__ xb) {
  int t = blockIdx.x;
  int din = DIM >> (3 - tm[t]);          // multiple of 128, so float4-uniform
  int d = threadIdx.x * 4;
  float4 v = *(const float4*)(x + (size_t)t * DIM + d);
  ushort4 o;
  if (d < din) {
    o.x = f2bf(v.x); o.y = f2bf(v.y); o.z = f2bf(v.z); o.w = f2bf(v.w);
  } else {
    o.x = 0; o.y = 0; o.z = 0; o.w = 0;
  }
  *(ushort4*)(xb + (size_t)t * DIM + d) = o;
}

__global__ void cvt_w_kernel(const float* __restrict__ src,
                             unsigned short* __restrict__ dst) {
  int i = (blockIdx.x * 256 + threadIdx.x) * 4;   // grid sized exactly
  float4 v = *(const float4*)(src + i);
  ushort4 o;
  o.x = f2bf(v.x); o.y = f2bf(v.y); o.z = f2bf(v.z); o.w = f2bf(v.w);
  *(ushort4*)(dst + i) = o;
}

extern "C" void kernel_launch(void* const* d_in, const int* in_sizes, int n_in,
                              void* d_out, int out_size, void* d_ws, size_t ws_size,
                              hipStream_t stream) {
  const float* x  = (const float*)d_in[0];
  const float* w1 = (const float*)d_in[1];
  const float* b1 = (const float*)d_in[2];
  const float* w2 = (const float*)d_in[3];
  const float* b2 = (const float*)d_in[4];
  const int*   tm = (const int*)d_in[5];
  float* out = (float*)d_out;

  char* ws = (char*)d_ws;
  unsigned short* xb  = (unsigned short*)(ws);              // 32 MB
  unsigned short* w1b = (unsigned short*)(ws + 33554432);   //  8 MB
  unsigned short* w2b = (unsigned short*)(ws + 41943040);   //  8 MB
  unsigned short* hb  = (unsigned short*)(ws + 50331648);   // 128 MB  (total 176 MB)

  cvt_x_kernel<<<M_TOK, 256, 0, stream>>>(x, tm, xb);
  cvt_w_kernel<<<(HID * DIM) / 1024, 256, 0, stream>>>(w1, w1b);
  cvt_w_kernel<<<(DIM * HID) / 1024, 256, 0, stream>>>(w2, w2b);

  gemm1_kernel<<<dim3(M_TOK / 128, HID / 128), 256, 0, stream>>>(xb, w1b, b1, hb);
  gemm2_kernel<<<dim3(M_TOK / 128, DIM / 128), 256, 0, stream>>>(hb, w2b, b2, tm, out);
}